// Round 4
// baseline (1918.453 us; speedup 1.0000x reference)
//
#include <hip/hip_runtime.h>

#define S_LEN 1024
#define BATCH 128

using u16 = unsigned short;
using u32 = unsigned int;
typedef _Float16 f16;
typedef __attribute__((ext_vector_type(2))) _Float16 f16x2;
typedef __attribute__((ext_vector_type(8))) _Float16 f16x8;
typedef __attribute__((ext_vector_type(4))) float floatx4;

__device__ __forceinline__ float fexp(float x) {
    return __builtin_amdgcn_exp2f(x * 1.4426950408889634f);
}
__device__ __forceinline__ float fsigmoid(float x) {
    return __builtin_amdgcn_rcpf(1.f + fexp(-x));
}
__device__ __forceinline__ float ftanh(float x) {
    return 1.f - 2.f * __builtin_amdgcn_rcpf(fexp(2.f * x) + 1.f);
}

// ---------------- prep: fp32 weights -> f16, bias sums ----------------
__global__ __launch_bounds__(256) void prep_kernel(
        const float* __restrict__ Wih0, const float* __restrict__ Whh0f,
        const float* __restrict__ Wih1, const float* __restrict__ Whh1f,
        const float* __restrict__ bih0, const float* __restrict__ bhh0,
        const float* __restrict__ bih1, const float* __restrict__ bhh1,
        f16* __restrict__ W0, f16* __restrict__ W1,
        f16* __restrict__ Wh0, f16* __restrict__ Wh1,
        float* __restrict__ b0, float* __restrict__ b1) {
    int i = blockIdx.x * 256 + threadIdx.x;
    if (i < 131072) {               // 2*512*128
        W0[i]  = (f16)Wih0[i];
        Wh0[i] = (f16)Whh0f[i];
        Wh1[i] = (f16)Whh1f[i];
    }
    if (i < 262144) W1[i] = (f16)Wih1[i];   // 2*512*256
    if (i < 1024) { b0[i] = bih0[i] + bhh0[i]; b1[i] = bih1[i] + bhh1[i]; }
}

// ---------------- chunked projection GEMM ----------------
// xgc[dir][l][0..511] = A_row(sidx,b) @ W[dir*512+?]^T + bias; l = ls*128+b,
// sidx = dir ? s0b-ls : s0+ls. GATHER: A_row = f16(emb[inputs[b][sidx]]).
template<int K, bool GATHER>
__global__ __launch_bounds__(256) void proj_chunk(
        const f16* __restrict__ A, const int* __restrict__ inputs,
        const float* __restrict__ emb, const f16* __restrict__ Bw,
        const float* __restrict__ bias, f16* __restrict__ C,
        int s0, int s0b, int CH) {
    __shared__ __align__(16) f16 As[128][72];   // +8 pad, 144B row stride
    __shared__ __align__(16) f16 Bs[128][72];
    const int t = threadIdx.x;
    // T1 bijective XCD remap (nwg = 8*CH, %8==0)
    const u32 nwg8 = gridDim.x >> 3;
    const u32 bid = (blockIdx.x & 7) * nwg8 + (blockIdx.x >> 3);
    const u32 per_dir = (u32)CH * 4;
    const int dir = (int)(bid / per_dir);
    const u32 rr = bid % per_dir;
    const int mt = (int)(rr >> 2);
    const int n0 = (int)(rr & 3) * 128;
    const int lane = t & 63, wid = t >> 6;
    const int wm = wid >> 1, wn = wid & 1;
    const int lrow = lane & 15;
    const int lk8  = (lane >> 4) * 8;

    floatx4 acc[4][4] = {};

    const int srow = t >> 3;        // 0..31
    const int scol = (t & 7) * 8;   // 0..56
    for (int k0 = 0; k0 < K; k0 += 64) {
        __syncthreads();
        #pragma unroll
        for (int r = 0; r < 4; ++r) {
            int row = srow + r * 32;
            int l = mt * 128 + row;
            int bb = l & 127, ls = l >> 7;
            int sidx = dir ? (s0b - ls) : (s0 + ls);
            if constexpr (GATHER) {
                int idx = inputs[bb * S_LEN + sidx];
                const float* ep = emb + (size_t)idx * 128 + k0 + scol;
                float4 v0 = *reinterpret_cast<const float4*>(ep);
                float4 v1 = *reinterpret_cast<const float4*>(ep + 4);
                f16x8 o = { (f16)v0.x, (f16)v0.y, (f16)v0.z, (f16)v0.w,
                            (f16)v1.x, (f16)v1.y, (f16)v1.z, (f16)v1.w };
                *reinterpret_cast<f16x8*>(&As[row][scol]) = o;
            } else {
                uint4 av = *reinterpret_cast<const uint4*>(
                    A + (size_t)(sidx * 128 + bb) * K + k0 + scol);
                *reinterpret_cast<uint4*>(&As[row][scol]) = av;
            }
            uint4 bv = *reinterpret_cast<const uint4*>(
                Bw + (size_t)(dir * 512 + n0 + row) * K + k0 + scol);
            *reinterpret_cast<uint4*>(&Bs[row][scol]) = bv;
        }
        __syncthreads();
        #pragma unroll
        for (int ks = 0; ks < 2; ++ks) {
            f16x8 af[4], bf[4];
            #pragma unroll
            for (int f = 0; f < 4; ++f) {
                af[f] = *reinterpret_cast<const f16x8*>(&As[wm * 64 + f * 16 + lrow][ks * 32 + lk8]);
                bf[f] = *reinterpret_cast<const f16x8*>(&Bs[wn * 64 + f * 16 + lrow][ks * 32 + lk8]);
            }
            #pragma unroll
            for (int fm = 0; fm < 4; ++fm)
                #pragma unroll
                for (int fn = 0; fn < 4; ++fn)
                    acc[fm][fn] = __builtin_amdgcn_mfma_f32_16x16x32_f16(
                        af[fm], bf[fn], acc[fm][fn], 0, 0, 0);
        }
    }
    // epilogue: C/D layout col=lane&15, row=(lane>>4)*4+reg  [m89, dtype-independent]
    f16* Cd = C + (size_t)dir * CH * 128 * 512;
    #pragma unroll
    for (int fn = 0; fn < 4; ++fn) {
        int col = n0 + wn * 64 + fn * 16 + lrow;          // 0..511 within dir
        float bv = bias[dir * 512 + col];
        #pragma unroll
        for (int fm = 0; fm < 4; ++fm) {
            int rowl = mt * 128 + wm * 64 + fm * 16 + (lane >> 4) * 4;
            #pragma unroll
            for (int r = 0; r < 4; ++r) {
                float v = acc[fm][fn][r] + bv;
                Cd[(size_t)(rowl + r) * 512 + col] = (f16)v;
            }
        }
    }
}

// ---------------- LSTM recurrence (one S-chunk) ----------------
// One WG per (dir, batch-row): 256 WGs = 1/CU, 512 threads, thread t owns gate row j=t.
// Whh row held in 16 NAMED f16x8 variables (cannot be demoted to scratch — R3's
// VGPR_Count=48 proved the lambda-captured array was scratch-backed). Matvec:
// 16 statically-unrolled f16x8 elementwise-fma -> 64 v_pk_fma_f16 / step, 4 chains.
// h broadcast via uniform-address ds_read_b128. Raw barriers (lgkmcnt-only fencing).
#define LSTM_STEP(LI, XV) do {                                                  \
    const f16x8* hp = reinterpret_cast<const f16x8*>(h16);                      \
    f16x8 aA = hp[0] * w0_;                                                     \
    f16x8 aB = hp[1] * w1_;                                                     \
    f16x8 aC = hp[2] * w2_;                                                     \
    f16x8 aD = hp[3] * w3_;                                                     \
    aA = __builtin_elementwise_fma(hp[4],  w4_, aA);                            \
    aB = __builtin_elementwise_fma(hp[5],  w5_, aB);                            \
    aC = __builtin_elementwise_fma(hp[6],  w6_, aC);                            \
    aD = __builtin_elementwise_fma(hp[7],  w7_, aD);                            \
    aA = __builtin_elementwise_fma(hp[8],  w8_, aA);                            \
    aB = __builtin_elementwise_fma(hp[9],  w9_, aB);                            \
    aC = __builtin_elementwise_fma(hp[10], wA_, aC);                            \
    aD = __builtin_elementwise_fma(hp[11], wB_, aD);                            \
    aA = __builtin_elementwise_fma(hp[12], wC_, aA);                            \
    aB = __builtin_elementwise_fma(hp[13], wD_, aB);                            \
    aC = __builtin_elementwise_fma(hp[14], wE_, aC);                            \
    aD = __builtin_elementwise_fma(hp[15], wF_, aD);                            \
    f16x8 s8 = (aA + aB) + (aC + aD);                                           \
    f16x2 s2 = (f16x2{s8[0], s8[1]} + f16x2{s8[2], s8[3]})                      \
             + (f16x2{s8[4], s8[5]} + f16x2{s8[6], s8[7]});                     \
    float g = (float)(XV) + (float)s2[0] + (float)s2[1];                        \
    float a = ((t >> 7) == 2) ? ftanh(g) : fsigmoid(g);                         \
    act_lds[t] = a;                                                             \
    asm volatile("s_waitcnt lgkmcnt(0)" ::: "memory");                          \
    __builtin_amdgcn_s_barrier();                                               \
    asm volatile("" ::: "memory");                                              \
    if (t < 128) {                                                              \
        float ai = act_lds[t], af = act_lds[t + 128];                           \
        float ag = act_lds[t + 256], ao = act_lds[t + 384];                     \
        c = af * c + ai * ag;                                                   \
        float hn = ao * ftanh(c);                                               \
        h16[t] = (f16)hn;                                                       \
        if (LAYER == 0) {                                                       \
            int sidx = dir ? (s0b - (LI)) : (s0 + (LI));                        \
            hs_out[(size_t)(sidx * BATCH + b) * 256 + dir * 128 + t] = (f16)hn; \
        }                                                                       \
    }                                                                           \
    asm volatile("s_waitcnt lgkmcnt(0)" ::: "memory");                          \
    __builtin_amdgcn_s_barrier();                                               \
    asm volatile("" ::: "memory");                                              \
} while (0)

template<int LAYER>
__global__ __launch_bounds__(512, 2) void recur_chunk(
        const f16* __restrict__ xgc,    // [2][CH*128][512]
        const f16* __restrict__ Whh,    // [1024][128] f16
        f16* __restrict__ hs_out,       // LAYER 0: [S*B][256]
        float* __restrict__ h_state,    // [2*128][128]
        float* __restrict__ c_state,    // [2*128][128]
        int s0, int s0b, int CH, int first) {
    const int t = threadIdx.x;
    const int dir = blockIdx.x >> 7;
    const int b = blockIdx.x & 127;

    __shared__ __align__(16) f16 h16[128];
    __shared__ float act_lds[512];

    const f16x8* wp8 = reinterpret_cast<const f16x8*>(Whh + (size_t)(dir * 512 + t) * 128);
    f16x8 w0_ = wp8[0],  w1_ = wp8[1],  w2_ = wp8[2],  w3_ = wp8[3];
    f16x8 w4_ = wp8[4],  w5_ = wp8[5],  w6_ = wp8[6],  w7_ = wp8[7];
    f16x8 w8_ = wp8[8],  w9_ = wp8[9],  wA_ = wp8[10], wB_ = wp8[11];
    f16x8 wC_ = wp8[12], wD_ = wp8[13], wE_ = wp8[14], wF_ = wp8[15];

    const int sbase = (dir * 128 + b) * 128 + (t & 127);
    float c = 0.f;
    if (t < 128) {
        if (first) { h16[t] = (f16)0.f; }
        else       { h16[t] = (f16)h_state[sbase]; c = c_state[sbase]; }
    }
    __syncthreads();

    const f16* xbase = xgc + ((size_t)(dir * CH) * 128 + b) * 512 + t;
    auto xaddr = [&](int li) -> const f16* {
        return xbase + (size_t)li * (128 * 512);
    };

    // depth-2 prefetch, unrolled by 2 (static rotation by naming)
    f16 xa = *xaddr(0);
    f16 xb_ = *xaddr(CH > 1 ? 1 : 0);
    for (int li = 0; li < CH; li += 2) {
        f16 xc = *xaddr(li + 2 < CH ? li + 2 : CH - 1);
        LSTM_STEP(li, xa);
        f16 xd = *xaddr(li + 3 < CH ? li + 3 : CH - 1);
        LSTM_STEP(li + 1, xb_);
        xa = xc; xb_ = xd;
    }
    if (t < 128) {
        h_state[sbase] = (float)h16[t];
        c_state[sbase] = c;
    }
}

// ---------------- decoder ----------------
__global__ __launch_bounds__(64) void decode_kernel(
        const float* __restrict__ h_state, const float* __restrict__ decW,
        const float* __restrict__ decb, const float* __restrict__ fc1W,
        const float* __restrict__ fc1b, float* __restrict__ out) {
    __shared__ float t1[64];
    int b = blockIdx.x, j = threadIdx.x;
    float acc = decb[j];
    const float* h0 = h_state + (size_t)b * 128;           // dir0
    const float* h1 = h_state + (size_t)(128 + b) * 128;   // dir1
    const float* wr = decW + (size_t)j * 256;
    #pragma unroll 4
    for (int k = 0; k < 128; ++k) acc += h0[k] * wr[k];
    #pragma unroll 4
    for (int k = 0; k < 128; ++k) acc += h1[k] * wr[128 + k];
    t1[j] = acc;
    __syncthreads();
    if (j < 2) {
        float o = fc1b[j];
        #pragma unroll
        for (int k = 0; k < 64; ++k) o += t1[k] * fc1W[j * 64 + k];
        out[b * 2 + j] = o;
    }
}

extern "C" void kernel_launch(void* const* d_in, const int* in_sizes, int n_in,
                              void* d_out, int out_size, void* d_ws, size_t ws_size,
                              hipStream_t stream) {
    const int*   inputs = (const int*)d_in[0];
    const float* emb    = (const float*)d_in[1];
    const float* Wih0   = (const float*)d_in[2];
    const float* Whh0   = (const float*)d_in[3];
    const float* bih0   = (const float*)d_in[4];
    const float* bhh0   = (const float*)d_in[5];
    const float* Wih1   = (const float*)d_in[6];
    const float* Whh1   = (const float*)d_in[7];
    const float* bih1   = (const float*)d_in[8];
    const float* bhh1   = (const float*)d_in[9];
    const float* decW   = (const float*)d_in[10];
    const float* decb   = (const float*)d_in[11];
    const float* fc1W   = (const float*)d_in[12];
    const float* fc1b   = (const float*)d_in[13];
    float* out = (float*)d_out;

    char* ws = (char*)d_ws;
    size_t off = 0;
    auto alloc = [&](size_t bytes) {
        char* p = ws + off;
        off = (off + bytes + 255) & ~(size_t)255;
        return p;
    };
    f16*   W0      = (f16*)alloc((size_t)131072 * 2);
    f16*   W1      = (f16*)alloc((size_t)262144 * 2);
    f16*   Wh0     = (f16*)alloc((size_t)131072 * 2);
    f16*   Wh1     = (f16*)alloc((size_t)131072 * 2);
    float* b0      = (float*)alloc(1024 * 4);
    float* b1      = (float*)alloc(1024 * 4);
    float* h_state = (float*)alloc((size_t)2 * 128 * 128 * 4);
    float* c_state = (float*)alloc((size_t)2 * 128 * 128 * 4);
    f16*   hs0     = (f16*)alloc((size_t)131072 * 256 * 2);   // 64 MiB
    size_t fixed_end = off;

    // pick the largest S-chunk whose xg buffer fits the remaining workspace
    int CH = 32;
    size_t avail = (ws_size > fixed_end) ? (ws_size - fixed_end) : 0;
    for (int c = 1024; c >= 32; c >>= 1) {
        if ((size_t)c * 262144 <= avail) { CH = c; break; }
    }
    f16* xgc = (f16*)alloc((size_t)CH * 262144);   // [2][CH*128][512] f16
    const int NC = S_LEN / CH;

    prep_kernel<<<1024, 256, 0, stream>>>(Wih0, Whh0, Wih1, Whh1,
                                          bih0, bhh0, bih1, bhh1,
                                          W0, W1, Wh0, Wh1, b0, b1);
    for (int ci = 0; ci < NC; ++ci) {
        int s0 = ci * CH, s0b = S_LEN - 1 - ci * CH;
        proj_chunk<128, true><<<8 * CH, 256, 0, stream>>>(
            nullptr, inputs, emb, W0, b0, xgc, s0, s0b, CH);
        recur_chunk<0><<<256, 512, 0, stream>>>(
            xgc, Wh0, hs0, h_state, c_state, s0, s0b, CH, ci == 0);
    }
    for (int ci = 0; ci < NC; ++ci) {
        int s0 = ci * CH, s0b = S_LEN - 1 - ci * CH;
        proj_chunk<256, false><<<8 * CH, 256, 0, stream>>>(
            hs0, nullptr, nullptr, W1, b1, xgc, s0, s0b, CH);
        recur_chunk<1><<<256, 512, 0, stream>>>(
            xgc, Wh1, nullptr, h_state, c_state, s0, s0b, CH, ci == 0);
    }
    decode_kernel<<<128, 64, 0, stream>>>(h_state, decW, decb, fc1W, fc1b, out);
}

// Round 6
// 1821.503 us; speedup vs baseline: 1.0532x; 1.0532x over previous
//
#include <hip/hip_runtime.h>

#define S_LEN 1024
#define BATCH 128

using u16 = unsigned short;
using u32 = unsigned int;
typedef _Float16 f16;
typedef __attribute__((ext_vector_type(2))) _Float16 f16x2;
typedef __attribute__((ext_vector_type(8))) _Float16 f16x8;
typedef __attribute__((ext_vector_type(4))) float floatx4;
typedef __attribute__((ext_vector_type(4))) u32 u32x4;

__device__ __forceinline__ float fexp(float x) {
    return __builtin_amdgcn_exp2f(x * 1.4426950408889634f);
}
__device__ __forceinline__ float fsigmoid(float x) {
    return __builtin_amdgcn_rcpf(1.f + fexp(-x));
}
__device__ __forceinline__ float ftanh(float x) {
    return 1.f - 2.f * __builtin_amdgcn_rcpf(fexp(2.f * x) + 1.f);
}

// ---------------- prep: fp32 weights -> f16, bias sums ----------------
__global__ __launch_bounds__(256) void prep_kernel(
        const float* __restrict__ Wih0, const float* __restrict__ Whh0f,
        const float* __restrict__ Wih1, const float* __restrict__ Whh1f,
        const float* __restrict__ bih0, const float* __restrict__ bhh0,
        const float* __restrict__ bih1, const float* __restrict__ bhh1,
        f16* __restrict__ W0, f16* __restrict__ W1,
        f16* __restrict__ Wh0, f16* __restrict__ Wh1,
        float* __restrict__ b0, float* __restrict__ b1) {
    int i = blockIdx.x * 256 + threadIdx.x;
    if (i < 131072) {               // 2*512*128
        W0[i]  = (f16)Wih0[i];
        Wh0[i] = (f16)Whh0f[i];
        Wh1[i] = (f16)Whh1f[i];
    }
    if (i < 262144) W1[i] = (f16)Wih1[i];   // 2*512*256
    if (i < 1024) { b0[i] = bih0[i] + bhh0[i]; b1[i] = bih1[i] + bhh1[i]; }
}

// ---------------- chunked projection GEMM (unchanged from R3/R4) ----------------
template<int K, bool GATHER>
__global__ __launch_bounds__(256) void proj_chunk(
        const f16* __restrict__ A, const int* __restrict__ inputs,
        const float* __restrict__ emb, const f16* __restrict__ Bw,
        const float* __restrict__ bias, f16* __restrict__ C,
        int s0, int s0b, int CH) {
    __shared__ __align__(16) f16 As[128][72];   // +8 pad, 144B row stride
    __shared__ __align__(16) f16 Bs[128][72];
    const int t = threadIdx.x;
    const u32 nwg8 = gridDim.x >> 3;
    const u32 bid = (blockIdx.x & 7) * nwg8 + (blockIdx.x >> 3);
    const u32 per_dir = (u32)CH * 4;
    const int dir = (int)(bid / per_dir);
    const u32 rr = bid % per_dir;
    const int mt = (int)(rr >> 2);
    const int n0 = (int)(rr & 3) * 128;
    const int lane = t & 63, wid = t >> 6;
    const int wm = wid >> 1, wn = wid & 1;
    const int lrow = lane & 15;
    const int lk8  = (lane >> 4) * 8;

    floatx4 acc[4][4] = {};

    const int srow = t >> 3;
    const int scol = (t & 7) * 8;
    for (int k0 = 0; k0 < K; k0 += 64) {
        __syncthreads();
        #pragma unroll
        for (int r = 0; r < 4; ++r) {
            int row = srow + r * 32;
            int l = mt * 128 + row;
            int bb = l & 127, ls = l >> 7;
            int sidx = dir ? (s0b - ls) : (s0 + ls);
            if constexpr (GATHER) {
                int idx = inputs[bb * S_LEN + sidx];
                const float* ep = emb + (size_t)idx * 128 + k0 + scol;
                float4 v0 = *reinterpret_cast<const float4*>(ep);
                float4 v1 = *reinterpret_cast<const float4*>(ep + 4);
                f16x8 o = { (f16)v0.x, (f16)v0.y, (f16)v0.z, (f16)v0.w,
                            (f16)v1.x, (f16)v1.y, (f16)v1.z, (f16)v1.w };
                *reinterpret_cast<f16x8*>(&As[row][scol]) = o;
            } else {
                uint4 av = *reinterpret_cast<const uint4*>(
                    A + (size_t)(sidx * 128 + bb) * K + k0 + scol);
                *reinterpret_cast<uint4*>(&As[row][scol]) = av;
            }
            uint4 bv = *reinterpret_cast<const uint4*>(
                Bw + (size_t)(dir * 512 + n0 + row) * K + k0 + scol);
            *reinterpret_cast<uint4*>(&Bs[row][scol]) = bv;
        }
        __syncthreads();
        #pragma unroll
        for (int ks = 0; ks < 2; ++ks) {
            f16x8 af[4], bf[4];
            #pragma unroll
            for (int f = 0; f < 4; ++f) {
                af[f] = *reinterpret_cast<const f16x8*>(&As[wm * 64 + f * 16 + lrow][ks * 32 + lk8]);
                bf[f] = *reinterpret_cast<const f16x8*>(&Bs[wn * 64 + f * 16 + lrow][ks * 32 + lk8]);
            }
            #pragma unroll
            for (int fm = 0; fm < 4; ++fm)
                #pragma unroll
                for (int fn = 0; fn < 4; ++fn)
                    acc[fm][fn] = __builtin_amdgcn_mfma_f32_16x16x32_f16(
                        af[fm], bf[fn], acc[fm][fn], 0, 0, 0);
        }
    }
    f16* Cd = C + (size_t)dir * CH * 128 * 512;
    #pragma unroll
    for (int fn = 0; fn < 4; ++fn) {
        int col = n0 + wn * 64 + fn * 16 + lrow;
        float bv = bias[dir * 512 + col];
        #pragma unroll
        for (int fm = 0; fm < 4; ++fm) {
            int rowl = mt * 128 + wm * 64 + fm * 16 + (lane >> 4) * 4;
            #pragma unroll
            for (int r = 0; r < 4; ++r) {
                float v = acc[fm][fn][r] + bv;
                Cd[(size_t)(rowl + r) * 512 + col] = (f16)v;
            }
        }
    }
}

// ---------------- LSTM recurrence v3 ----------------
// 256 threads (4 waves, 1/SIMD), WG per (dir,b). Thread t: unit u=(t>>6)*32+(t&31);
// lo half-wave owns gate rows (u, u+256)=(i,g), hi half (u+128, u+384)=(f,o).
// 32 u32x4 weight granules pinned live via asm "+v" (non-rematerializable).
// Act exchange via 2x shfl_xor(32) — no act_lds. h double-buffered (512B LDS),
// ONE barrier/step. HVAR=0: 16 uniform ds_read_b128/step. HVAR=1: 1 lane-spread
// ds_read_b128 + 64 v_readlane -> h in SGPRs, v_pk_fma_f16 with "s" operand.

#define MACB(HV, QA, QB) {                                           \
    f16x8 h8  = __builtin_bit_cast(f16x8, HV);                       \
    f16x8 wa8 = __builtin_bit_cast(f16x8, QA);                       \
    f16x8 wb8 = __builtin_bit_cast(f16x8, QB);                       \
    ca0 += f16x2{h8[0],h8[1]} * f16x2{wa8[0],wa8[1]};                \
    cb0 += f16x2{h8[0],h8[1]} * f16x2{wb8[0],wb8[1]};                \
    ca1 += f16x2{h8[2],h8[3]} * f16x2{wa8[2],wa8[3]};                \
    cb1 += f16x2{h8[2],h8[3]} * f16x2{wb8[2],wb8[3]};                \
    ca2 += f16x2{h8[4],h8[5]} * f16x2{wa8[4],wa8[5]};                \
    cb2 += f16x2{h8[4],h8[5]} * f16x2{wb8[4],wb8[5]};                \
    ca3 += f16x2{h8[6],h8[7]} * f16x2{wa8[6],wa8[7]};                \
    cb3 += f16x2{h8[6],h8[7]} * f16x2{wb8[6],wb8[7]};                \
}

#define MACA(J, QA, QB) {                                                        \
    u32 h0_ = (u32)__builtin_amdgcn_readlane((int)hvA[0], J);                    \
    u32 h1_ = (u32)__builtin_amdgcn_readlane((int)hvA[1], J);                    \
    u32 h2_ = (u32)__builtin_amdgcn_readlane((int)hvA[2], J);                    \
    u32 h3_ = (u32)__builtin_amdgcn_readlane((int)hvA[3], J);                    \
    asm("v_pk_fma_f16 %0, %1, %2, %0" : "+v"(ua0) : "v"(QA[0]), "s"(h0_));       \
    asm("v_pk_fma_f16 %0, %1, %2, %0" : "+v"(ub0) : "v"(QB[0]), "s"(h0_));       \
    asm("v_pk_fma_f16 %0, %1, %2, %0" : "+v"(ua1) : "v"(QA[1]), "s"(h1_));       \
    asm("v_pk_fma_f16 %0, %1, %2, %0" : "+v"(ub1) : "v"(QB[1]), "s"(h1_));       \
    asm("v_pk_fma_f16 %0, %1, %2, %0" : "+v"(ua2) : "v"(QA[2]), "s"(h2_));       \
    asm("v_pk_fma_f16 %0, %1, %2, %0" : "+v"(ub2) : "v"(QB[2]), "s"(h2_));       \
    asm("v_pk_fma_f16 %0, %1, %2, %0" : "+v"(ua3) : "v"(QA[3]), "s"(h3_));       \
    asm("v_pk_fma_f16 %0, %1, %2, %0" : "+v"(ub3) : "v"(QB[3]), "s"(h3_));       \
}

#define LSTM_STEP(CUR, NXT, LI, XV0, XV1) {                                     \
    f16x2 ra, rb;                                                               \
    if constexpr (HVAR == 0) {                                                  \
        const u32x4* hb = reinterpret_cast<const u32x4*>(&h16[CUR][0]);         \
        u32x4 hv0 = hb[0],  hv1 = hb[1],  hv2 = hb[2],  hv3 = hb[3];            \
        u32x4 hv4 = hb[4],  hv5 = hb[5],  hv6 = hb[6],  hv7 = hb[7];            \
        u32x4 hv8 = hb[8],  hv9 = hb[9],  hvA_ = hb[10], hvB_ = hb[11];         \
        u32x4 hvC_ = hb[12], hvD_ = hb[13], hvE_ = hb[14], hvF_ = hb[15];       \
        f16x2 ca0{}, ca1{}, ca2{}, ca3{}, cb0{}, cb1{}, cb2{}, cb3{};           \
        MACB(hv0,  qa0,  qb0)  MACB(hv1,  qa1,  qb1)                            \
        MACB(hv2,  qa2,  qb2)  MACB(hv3,  qa3,  qb3)                            \
        MACB(hv4,  qa4,  qb4)  MACB(hv5,  qa5,  qb5)                            \
        MACB(hv6,  qa6,  qb6)  MACB(hv7,  qa7,  qb7)                            \
        MACB(hv8,  qa8,  qb8)  MACB(hv9,  qa9,  qb9)                            \
        MACB(hvA_, qa10, qb10) MACB(hvB_, qa11, qb11)                           \
        MACB(hvC_, qa12, qb12) MACB(hvD_, qa13, qb13)                           \
        MACB(hvE_, qa14, qb14) MACB(hvF_, qa15, qb15)                           \
        ra = (ca0 + ca1) + (ca2 + ca3);                                         \
        rb = (cb0 + cb1) + (cb2 + cb3);                                         \
    } else {                                                                    \
        u32x4 hvA = reinterpret_cast<const u32x4*>(&h16[CUR][0])[t & 15];       \
        u32 ua0 = 0, ua1 = 0, ua2 = 0, ua3 = 0;                                 \
        u32 ub0 = 0, ub1 = 0, ub2 = 0, ub3 = 0;                                 \
        MACA(0,  qa0,  qb0)  MACA(1,  qa1,  qb1)                                \
        MACA(2,  qa2,  qb2)  MACA(3,  qa3,  qb3)                                \
        MACA(4,  qa4,  qb4)  MACA(5,  qa5,  qb5)                                \
        MACA(6,  qa6,  qb6)  MACA(7,  qa7,  qb7)                                \
        MACA(8,  qa8,  qb8)  MACA(9,  qa9,  qb9)                                \
        MACA(10, qa10, qb10) MACA(11, qa11, qb11)                               \
        MACA(12, qa12, qb12) MACA(13, qa13, qb13)                               \
        MACA(14, qa14, qb14) MACA(15, qa15, qb15)                               \
        ra = (__builtin_bit_cast(f16x2, ua0) + __builtin_bit_cast(f16x2, ua1))  \
           + (__builtin_bit_cast(f16x2, ua2) + __builtin_bit_cast(f16x2, ua3)); \
        rb = (__builtin_bit_cast(f16x2, ub0) + __builtin_bit_cast(f16x2, ub1))  \
           + (__builtin_bit_cast(f16x2, ub2) + __builtin_bit_cast(f16x2, ub3)); \
    }                                                                           \
    float g0 = (float)(XV0) + (float)ra[0] + (float)ra[1];                      \
    float g1 = (float)(XV1) + (float)rb[0] + (float)rb[1];                      \
    float a0 = fsigmoid(g0);                          /* i (lo) or f (hi) */    \
    float a1 = hi ? fsigmoid(g1) : ftanh(g1);         /* o (hi) or g (lo) */    \
    float r0 = __shfl_xor(a0, 32, 64);                                          \
    float r1 = __shfl_xor(a1, 32, 64);                                          \
    float a_i = hi ? r0 : a0;                                                   \
    float a_g = hi ? r1 : a1;                                                   \
    float a_f = hi ? a0 : r0;                                                   \
    float a_o = hi ? a1 : r1;                                                   \
    c = a_f * c + a_i * a_g;                                                    \
    float hn = a_o * ftanh(c);                                                  \
    if (!hi) {                                                                  \
        h16[NXT][u] = (f16)hn;                                                  \
        if (LAYER == 0) {                                                       \
            int sidx = dir ? (s0b - (LI)) : (s0 + (LI));                        \
            hs_out[(size_t)(sidx * BATCH + b) * 256 + dir * 128 + u] = (f16)hn; \
        }                                                                       \
    }                                                                           \
    hn_keep = hn;                                                               \
    asm volatile("s_waitcnt lgkmcnt(0)" ::: "memory");                          \
    __builtin_amdgcn_s_barrier();                                               \
    asm volatile("" ::: "memory");                                              \
}

template<int LAYER, int HVAR>
__global__ __launch_bounds__(256, 1) void recur_chunk(
        const f16* __restrict__ xgc,    // [2][CH*128][512]
        const f16* __restrict__ Whh,    // [1024][128] f16
        f16* __restrict__ hs_out,       // LAYER 0: [S*B][256]
        float* __restrict__ h_state,    // [2][128][128]
        float* __restrict__ c_state,    // [2][128][128]
        int s0, int s0b, int CH, int first) {
    const int t = threadIdx.x;
    const int dir = blockIdx.x >> 7;
    const int b = blockIdx.x & 127;
    const int u = ((t >> 6) << 5) + (t & 31);   // hidden unit 0..127
    const bool hi = (t & 32) != 0;              // gate half: lo=(i,g), hi=(f,o)
    const int wr0 = hi ? (u + 128) : u;         // within-dir gate rows
    const int wr1 = wr0 + 256;

    __shared__ __align__(16) f16 h16[2][128];

    // ---- weights: 32 granules, pinned live in VGPRs ----
    const u32x4* wp0 = reinterpret_cast<const u32x4*>(Whh + (size_t)(dir * 512 + wr0) * 128);
    const u32x4* wp1 = reinterpret_cast<const u32x4*>(Whh + (size_t)(dir * 512 + wr1) * 128);
    u32x4 qa0 = wp0[0],  qa1 = wp0[1],  qa2 = wp0[2],  qa3 = wp0[3];
    u32x4 qa4 = wp0[4],  qa5 = wp0[5],  qa6 = wp0[6],  qa7 = wp0[7];
    u32x4 qa8 = wp0[8],  qa9 = wp0[9],  qa10 = wp0[10], qa11 = wp0[11];
    u32x4 qa12 = wp0[12], qa13 = wp0[13], qa14 = wp0[14], qa15 = wp0[15];
    u32x4 qb0 = wp1[0],  qb1 = wp1[1],  qb2 = wp1[2],  qb3 = wp1[3];
    u32x4 qb4 = wp1[4],  qb5 = wp1[5],  qb6 = wp1[6],  qb7 = wp1[7];
    u32x4 qb8 = wp1[8],  qb9 = wp1[9],  qb10 = wp1[10], qb11 = wp1[11];
    u32x4 qb12 = wp1[12], qb13 = wp1[13], qb14 = wp1[14], qb15 = wp1[15];
    asm volatile("" : "+v"(qa0), "+v"(qa1), "+v"(qa2),  "+v"(qa3),
                      "+v"(qa4), "+v"(qa5), "+v"(qa6),  "+v"(qa7),
                      "+v"(qa8), "+v"(qa9), "+v"(qa10), "+v"(qa11),
                      "+v"(qa12), "+v"(qa13), "+v"(qa14), "+v"(qa15));
    asm volatile("" : "+v"(qb0), "+v"(qb1), "+v"(qb2),  "+v"(qb3),
                      "+v"(qb4), "+v"(qb5), "+v"(qb6),  "+v"(qb7),
                      "+v"(qb8), "+v"(qb9), "+v"(qb10), "+v"(qb11),
                      "+v"(qb12), "+v"(qb13), "+v"(qb14), "+v"(qb15));

    // ---- state init ----
    const int sb = (dir * 128 + b) * 128 + u;
    float c = first ? 0.f : c_state[sb];
    if (!hi) h16[0][u] = first ? (f16)0.f : (f16)h_state[sb];
    __syncthreads();

    // ---- xg pointers: 2 gate rows, stride 128*512 per step ----
    const f16* xp0 = xgc + ((size_t)(dir * CH) * 128 + b) * 512 + wr0;
    const f16* xp1 = xgc + ((size_t)(dir * CH) * 128 + b) * 512 + wr1;

    float hn_keep = 0.f;
    // depth-2 prefetch, unrolled by 2 (static buffer parity, static rotation)
    f16 xa0 = xp0[0], xa1 = xp1[0];
    int i1 = CH > 1 ? 1 : 0;
    f16 xb0 = xp0[(size_t)i1 * 65536], xb1 = xp1[(size_t)i1 * 65536];
    for (int li = 0; li < CH; li += 2) {
        size_t o2 = (size_t)(li + 2 < CH ? li + 2 : CH - 1) * 65536;
        f16 xc0 = xp0[o2], xc1 = xp1[o2];
        LSTM_STEP(0, 1, li, xa0, xa1);
        size_t o3 = (size_t)(li + 3 < CH ? li + 3 : CH - 1) * 65536;
        f16 xd0 = xp0[o3], xd1 = xp1[o3];
        LSTM_STEP(1, 0, li + 1, xb0, xb1);
        xa0 = xc0; xa1 = xc1; xb0 = xd0; xb1 = xd1;
    }
    if (!hi) {
        h_state[sb] = (float)(f16)hn_keep;
        c_state[sb] = c;
    }
}

// ---------------- decoder ----------------
__global__ __launch_bounds__(64) void decode_kernel(
        const float* __restrict__ h_state, const float* __restrict__ decW,
        const float* __restrict__ decb, const float* __restrict__ fc1W,
        const float* __restrict__ fc1b, float* __restrict__ out) {
    __shared__ float t1[64];
    int b = blockIdx.x, j = threadIdx.x;
    float acc = decb[j];
    const float* h0 = h_state + (size_t)b * 128;           // dir0
    const float* h1 = h_state + (size_t)(128 + b) * 128;   // dir1
    const float* wr = decW + (size_t)j * 256;
    #pragma unroll 4
    for (int k = 0; k < 128; ++k) acc += h0[k] * wr[k];
    #pragma unroll 4
    for (int k = 0; k < 128; ++k) acc += h1[k] * wr[128 + k];
    t1[j] = acc;
    __syncthreads();
    if (j < 2) {
        float o = fc1b[j];
        #pragma unroll
        for (int k = 0; k < 64; ++k) o += t1[k] * fc1W[j * 64 + k];
        out[b * 2 + j] = o;
    }
}

extern "C" void kernel_launch(void* const* d_in, const int* in_sizes, int n_in,
                              void* d_out, int out_size, void* d_ws, size_t ws_size,
                              hipStream_t stream) {
    const int*   inputs = (const int*)d_in[0];
    const float* emb    = (const float*)d_in[1];
    const float* Wih0   = (const float*)d_in[2];
    const float* Whh0   = (const float*)d_in[3];
    const float* bih0   = (const float*)d_in[4];
    const float* bhh0   = (const float*)d_in[5];
    const float* Wih1   = (const float*)d_in[6];
    const float* Whh1   = (const float*)d_in[7];
    const float* bih1   = (const float*)d_in[8];
    const float* bhh1   = (const float*)d_in[9];
    const float* decW   = (const float*)d_in[10];
    const float* decb   = (const float*)d_in[11];
    const float* fc1W   = (const float*)d_in[12];
    const float* fc1b   = (const float*)d_in[13];
    float* out = (float*)d_out;

    char* ws = (char*)d_ws;
    size_t off = 0;
    auto alloc = [&](size_t bytes) {
        char* p = ws + off;
        off = (off + bytes + 255) & ~(size_t)255;
        return p;
    };
    f16*   W0      = (f16*)alloc((size_t)131072 * 2);
    f16*   W1      = (f16*)alloc((size_t)262144 * 2);
    f16*   Wh0     = (f16*)alloc((size_t)131072 * 2);
    f16*   Wh1     = (f16*)alloc((size_t)131072 * 2);
    float* b0      = (float*)alloc(1024 * 4);
    float* b1      = (float*)alloc(1024 * 4);
    float* h_state = (float*)alloc((size_t)2 * 128 * 128 * 4);
    float* c_state = (float*)alloc((size_t)2 * 128 * 128 * 4);
    f16*   hs0     = (f16*)alloc((size_t)131072 * 256 * 2);   // 64 MiB
    size_t fixed_end = off;

    int CH = 32;
    size_t avail = (ws_size > fixed_end) ? (ws_size - fixed_end) : 0;
    for (int cc = 1024; cc >= 32; cc >>= 1) {
        if ((size_t)cc * 262144 <= avail) { CH = cc; break; }
    }
    f16* xgc = (f16*)alloc((size_t)CH * 262144);   // [2][CH*128][512] f16
    const int NC = S_LEN / CH;

    prep_kernel<<<1024, 256, 0, stream>>>(Wih0, Whh0, Wih1, Whh1,
                                          bih0, bhh0, bih1, bhh1,
                                          W0, W1, Wh0, Wh1, b0, b1);
    for (int ci = 0; ci < NC; ++ci) {
        int s0 = ci * CH, s0b = S_LEN - 1 - ci * CH;
        proj_chunk<128, true><<<8 * CH, 256, 0, stream>>>(
            nullptr, inputs, emb, W0, b0, xgc, s0, s0b, CH);
        recur_chunk<0, 0><<<256, 256, 0, stream>>>(
            xgc, Wh0, hs0, h_state, c_state, s0, s0b, CH, ci == 0);
    }
    for (int ci = 0; ci < NC; ++ci) {
        int s0 = ci * CH, s0b = S_LEN - 1 - ci * CH;
        proj_chunk<256, false><<<8 * CH, 256, 0, stream>>>(
            hs0, nullptr, nullptr, W1, b1, xgc, s0, s0b, CH);
        recur_chunk<1, 1><<<256, 256, 0, stream>>>(
            xgc, Wh1, nullptr, h_state, c_state, s0, s0b, CH, ci == 0);
    }
    decode_kernel<<<128, 64, 0, stream>>>(h_state, decW, decb, fc1W, fc1b, out);
}